// Round 16
// baseline (262.766 us; speedup 1.0000x reference)
//
#include <hip/hip_runtime.h>

typedef __bf16 bf16;
typedef __bf16 bf16x4 __attribute__((ext_vector_type(4)));
typedef __bf16 bf16x8 __attribute__((ext_vector_type(8)));
typedef float  f32x2  __attribute__((ext_vector_type(2)));
typedef float  f32x4  __attribute__((ext_vector_type(4)));

#define NEG_INF (-__builtin_inff())
#define L2E 1.44269504088896f
#define DEFER_THR 5.545177444479562f   /* 8 / log2(e): exp2 exponent bound 8 */

__device__ __forceinline__ void gl16(const void* g, void* l) {
    __builtin_amdgcn_global_load_lds(
        (const __attribute__((address_space(1))) void*)g,
        (__attribute__((address_space(3))) void*)l, 16, 0, 0);
}
__device__ __forceinline__ bf16x8 ld128(const char* p) {
    return *reinterpret_cast<const bf16x8*>(p);
}

// ---------------- fused prep: x split + W_qkv transpose-split + W_0 transpose ----------------
// grid 9216 x 256: [0,8192) split_x; [8192,8960) cvt_wqkv; [8960,9216) cvt_w0
__global__ void k_prep(const float* __restrict__ x,
                       const float* __restrict__ wq, const float* __restrict__ wk,
                       const float* __restrict__ wv, const float* __restrict__ w0,
                       bf16* __restrict__ xh, bf16* __restrict__ xl,
                       bf16* __restrict__ ohi, bf16* __restrict__ olo,
                       bf16* __restrict__ w0t) {
    __shared__ float tile[64][65];
    const int bid = blockIdx.x;
    const int t = threadIdx.x;
    if (bid < 8192) {
        int i = (bid * 256 + t) * 4;
        float4 v = *reinterpret_cast<const float4*>(x + i);
        float a[4] = {v.x, v.y, v.z, v.w};
        bf16x4 h, l;
        #pragma unroll
        for (int e = 0; e < 4; e++) {
            bf16 hh = (bf16)a[e];
            h[e] = hh;
            l[e] = (bf16)(a[e] - (float)hh);
        }
        *reinterpret_cast<bf16x4*>(xh + i) = h;
        *reinterpret_cast<bf16x4*>(xl + i) = l;
    } else if (bid < 8960) {
        const int idx = bid - 8192;
        const int d0 = (idx & 15) * 64, h = (idx >> 4) & 15, proj = idx >> 8;
        const float* w = (proj == 0) ? wq : ((proj == 1) ? wk : wv);
        {
            int k = t & 63, dr = t >> 6;
            #pragma unroll
            for (int i = 0; i < 16; i++) {
                int dl = i * 4 + dr;
                tile[dl][k] = w[(size_t)(h * 1024 + d0 + dl) * 64 + k];
            }
        }
        __syncthreads();
        {
            int dl = t & 63, kr = t >> 6;
            #pragma unroll
            for (int i = 0; i < 16; i++) {
                int k = i * 4 + kr;
                float v = tile[dl][k];
                bf16 hi = (bf16)v;
                size_t o = (size_t)(proj * 1024 + h * 64 + k) * 1024 + d0 + dl;
                ohi[o] = hi;
                olo[o] = (bf16)(v - (float)hi);
            }
        }
    } else {
        const int idx = bid - 8960;
        const int n0 = (idx & 15) * 64, c0 = (idx >> 4) * 64;
        {
            int n = t & 63, cr = t >> 6;
            #pragma unroll
            for (int i = 0; i < 16; i++) {
                int cl = i * 4 + cr;
                tile[cl][n] = w0[(size_t)(c0 + cl) * 1024 + n0 + n];
            }
        }
        __syncthreads();
        {
            int cl = t & 63, nr = t >> 6;
            #pragma unroll
            for (int i = 0; i < 16; i++) {
                int nl = i * 4 + nr;
                w0t[(size_t)(n0 + nl) * 1024 + c0 + cl] = (bf16)tile[cl][nl];
            }
        }
    }
}

// ---------------- projection GEMM, Q/K (split-bf16, 3-pass, gl_lds, BK=32) ----------------
// 32KB LDS -> 4 blocks/CU (16 waves/CU). Single-buffer 2-barrier schedule (r14),
// BK=32 staging/read geometry (r12-verified swizzle).
__global__ __launch_bounds__(256)
void k_gemm3(const bf16* __restrict__ Ah, const bf16* __restrict__ Al,
             const bf16* __restrict__ Bh, const bf16* __restrict__ Bl,
             bf16* __restrict__ Qhi, bf16* __restrict__ Qlo,
             bf16* __restrict__ Khi, bf16* __restrict__ Klo)
{
    __shared__ char LDS[32768];   // Ah | Al | Bh | Bl, 8KB each (128 rows x 64B)
    const int t = threadIdx.x;
    const int m0 = blockIdx.x * 128;
    const int n0 = blockIdx.y * 128;
    const int wid = t >> 6, lane = t & 63, lr = lane & 15, lg = lane >> 4;
    const int wm = wid >> 1, wn = wid & 1;

    // staging: lane covers row rr=lane>>2 of its 16-row group, slot sl=lane&3;
    // source column pre-swizzled: col8 = sl ^ ((rr>>1)&3)  [involution]
    const int rr = lane >> 2, sl = lane & 3;
    const int eoff = rr * 1024 + ((sl ^ ((rr >> 1) & 3)) * 8);
    const bf16* pAh = Ah + (size_t)m0 * 1024 + eoff;
    const bf16* pAl = Al + (size_t)m0 * 1024 + eoff;
    const bf16* pBh = Bh + (size_t)n0 * 1024 + eoff;
    const bf16* pBl = Bl + (size_t)n0 * 1024 + eoff;

    // read base: row lr, slot lg^swz(lr); rows advance by imm offsets (x64B)
    const int rb = lr * 64 + ((lg ^ ((lr >> 1) & 3)) << 4);

    f32x4 acc[4][4] = {};

    for (int k0 = 0; k0 < 1024; k0 += 32) {
        #pragma unroll
        for (int i = 0; i < 2; i++) {
            const int r0 = wid * 32 + i * 16;        // wave-uniform 16-row group
            const size_t g = (size_t)r0 * 1024 + k0;
            char* ld = LDS + r0 * 64;
            gl16(pAh + g, ld);
            gl16(pAl + g, ld + 8192);
            gl16(pBh + g, ld + 16384);
            gl16(pBl + g, ld + 24576);
        }
        __syncthreads();

        bf16x8 ah[4], al[4], bh[4], bl[4];
        #pragma unroll
        for (int mt = 0; mt < 4; mt++) {
            const int off = rb + (wm * 64 + mt * 16) * 64;
            ah[mt] = ld128(LDS + off);
            al[mt] = ld128(LDS + off + 8192);
        }
        #pragma unroll
        for (int nt = 0; nt < 4; nt++) {
            const int off = rb + (wn * 64 + nt * 16) * 64;
            bh[nt] = ld128(LDS + off + 16384);
            bl[nt] = ld128(LDS + off + 24576);
        }
        __builtin_amdgcn_s_setprio(1);
        #pragma unroll
        for (int mt = 0; mt < 4; mt++)
            #pragma unroll
            for (int nt = 0; nt < 4; nt++) {
                acc[mt][nt] = __builtin_amdgcn_mfma_f32_16x16x32_bf16(
                    ah[mt], bh[nt], acc[mt][nt], 0, 0, 0);
                acc[mt][nt] = __builtin_amdgcn_mfma_f32_16x16x32_bf16(
                    ah[mt], bl[nt], acc[mt][nt], 0, 0, 0);
                acc[mt][nt] = __builtin_amdgcn_mfma_f32_16x16x32_bf16(
                    al[mt], bh[nt], acc[mt][nt], 0, 0, 0);
            }
        __builtin_amdgcn_s_setprio(0);
        __syncthreads();
    }

    #pragma unroll
    for (int mt = 0; mt < 4; mt++)
        #pragma unroll
        for (int nt = 0; nt < 4; nt++)
            #pragma unroll
            for (int j = 0; j < 4; j++) {
                int m = m0 + wm * 64 + mt * 16 + lg * 4 + j;
                int n = n0 + wn * 64 + nt * 16 + lr;
                float v = acc[mt][nt][j];
                int b = m >> 11, s = m & 2047;
                if (n < 1024) {
                    int h = n >> 6, k = n & 63;
                    size_t idx = ((size_t)(b * 16 + h) * 2048 + s) * 64 + k;
                    float vs = v * 0.125f;
                    bf16 hi = (bf16)vs;
                    Qhi[idx] = hi;
                    Qlo[idx] = (bf16)(vs - (float)hi);
                } else {
                    int n2 = n - 1024, h = n2 >> 6, k = n2 & 63;
                    size_t idx = ((size_t)(b * 16 + h) * 2048 + s) * 64 + k;
                    bf16 hi = (bf16)v;
                    Khi[idx] = hi;
                    Klo[idx] = (bf16)(v - (float)hi);
                }
            }
}

// ---------------- 2-plane bf16 GEMM (gl_lds, BK=64, tile 128x64) ----------------
// LDS 24KB -> 4 blocks/CU at grid (64,16). MODE 0: V^T scatter; MODE 1: fp32 Out.
template<int MODE>
__global__ __launch_bounds__(256)
void k_gemm2(const bf16* __restrict__ A, const bf16* __restrict__ Bt,
             bf16* __restrict__ Vtb, float* __restrict__ Out)
{
    __shared__ char LDS[24576];   // A 16KB (128x128B) | B 8KB (64x128B)
    const int t = threadIdx.x;
    const int m0 = blockIdx.x * 128;
    const int n0 = blockIdx.y * 64;
    const int wid = t >> 6, lane = t & 63, lr = lane & 15, lg = lane >> 4;
    const int wm = wid >> 1, wn = wid & 1;   // wave tile: 64m x 32n

    const int eoff = (lane >> 3) * 1024 + (((lane & 7) ^ (lane >> 3)) * 8);
    const bf16* pA = A + (size_t)m0 * 1024 + eoff;
    const bf16* pB = Bt + (size_t)n0 * 1024 + eoff;

    f32x4 acc[4][2] = {};

    for (int k0 = 0; k0 < 1024; k0 += 64) {
        #pragma unroll
        for (int i = 0; i < 4; i++) {
            const int r0 = (wid * 4 + i) * 8;
            gl16(pA + (size_t)r0 * 1024 + k0, LDS + r0 * 128);
        }
        #pragma unroll
        for (int i = 0; i < 2; i++) {
            const int r0 = (wid * 2 + i) * 8;
            gl16(pB + (size_t)r0 * 1024 + k0, LDS + 16384 + r0 * 128);
        }
        __syncthreads();
        #pragma unroll
        for (int kk = 0; kk < 2; kk++) {
            bf16x8 af[4], bfr[2];
            #pragma unroll
            for (int mt = 0; mt < 4; mt++) {
                int row = wm * 64 + mt * 16 + lr;
                af[mt] = ld128(LDS + row * 128 + (((kk * 4 + lg) * 16) ^ ((row & 7) << 4)));
            }
            #pragma unroll
            for (int nt = 0; nt < 2; nt++) {
                int row = wn * 32 + nt * 16 + lr;
                bfr[nt] = ld128(LDS + 16384 + row * 128 + (((kk * 4 + lg) * 16) ^ ((row & 7) << 4)));
            }
            __builtin_amdgcn_s_setprio(1);
            #pragma unroll
            for (int mt = 0; mt < 4; mt++)
                #pragma unroll
                for (int nt = 0; nt < 2; nt++)
                    acc[mt][nt] = __builtin_amdgcn_mfma_f32_16x16x32_bf16(
                        af[mt], bfr[nt], acc[mt][nt], 0, 0, 0);
            __builtin_amdgcn_s_setprio(0);
        }
        __syncthreads();
    }

    #pragma unroll
    for (int mt = 0; mt < 4; mt++)
        #pragma unroll
        for (int nt = 0; nt < 2; nt++)
            #pragma unroll
            for (int j = 0; j < 4; j++) {
                int m = m0 + wm * 64 + mt * 16 + lg * 4 + j;
                int nl = n0 + wn * 32 + nt * 16 + lr;
                if (MODE == 0) {
                    int b = m >> 11, s = m & 2047;
                    int h = nl >> 6, dv = nl & 63;
                    Vtb[((size_t)(b * 16 + h) * 64 + dv) * 2048 + s] = (bf16)acc[mt][nt][j];
                } else {
                    Out[(size_t)m * 1024 + nl] = acc[mt][nt][j];
                }
            }
}

// ---------------- flash attention v10 (unchanged) ----------------
__global__ __launch_bounds__(512, 4)
void k_attn(const bf16* __restrict__ Qhi, const bf16* __restrict__ Qlo,
            const bf16* __restrict__ Khi, const bf16* __restrict__ Klo,
            const bf16* __restrict__ Vtb, bf16* __restrict__ hd)
{
    __shared__ char LDS[49152];   // buf (24K): K-hi | K-lo | V ; x2 buffers
    const int bid = blockIdx.x;
    const int x7 = bid & 7, k6 = bid >> 3;
    const int hh = k6 >> 3, pr = k6 & 7;
    const int bh = x7 * 8 + hh;
    const int t = threadIdx.x, wid = t >> 6, lane = t & 63, lr = lane & 15, lg = lane >> 4;
    const bf16* Qhp = Qhi + (size_t)bh * 131072;
    const bf16* Qlp = Qlo + (size_t)bh * 131072;
    const bf16* Kbase = Khi + (size_t)bh * 131072;
    const bf16* Lbase = Klo + (size_t)bh * 131072;
    const bf16* Vbase = Vtb + (size_t)bh * 131072;

    const int swc = (lr & 7) << 4;
    const int b0 = lr * 128 + ((lg * 16) ^ swc);
    const int b1 = lr * 128 + ((64 + lg * 16) ^ swc);

    const int r = t >> 3, c8 = t & 7;
    const int ssw = ((c8 ^ (r & 7)) * 8);
    const int kso = r * 64 + ssw;
    const int vso = r * 2048 + ssw;
    char* const ldst = (char*)LDS + (t >> 6) * 1024 + 0;

    #pragma unroll 1
    for (int pass = 0; pass < 2; pass++) {
        const int qB = pass ? pr : 15 - pr;
        const int q0 = qB * 128 + wid * 16;
        const int qdiv = q0 >> 6;
        const int kbmax = 2 * qB + 1;
        const int qg = q0 + lr;

        bf16x8 qh[2], ql[2];
        #pragma unroll
        for (int kk = 0; kk < 2; kk++) {
            size_t off = (size_t)(q0 + lr) * 64 + kk * 32 + lg * 8;
            qh[kk] = *reinterpret_cast<const bf16x8*>(Qhp + off);
            ql[kk] = *reinterpret_cast<const bf16x8*>(Qlp + off);
        }

        const bf16* gk = Kbase + kso;
        const bf16* gl = Lbase + kso;
        const bf16* gv = Vbase + vso;

        gl16(gk, ldst);
        gl16(gl, ldst + 8192);
        gl16(gv, ldst + 16384);
        __syncthreads();

        f32x4 accO[4] = {};
        float mrow = NEG_INF;
        float negmL2 = NEG_INF;
        f32x2 lsum2 = {0.0f, 0.0f};

        for (int kb = 0; kb <= kbmax; kb++) {
            const int ro = (kb & 1) ? 24576 : 0;
            const int wo = 24576 - ro;
            if (kb < kbmax) {
                gk += 4096; gl += 4096; gv += 64;
                gl16(gk, ldst + wo);
                gl16(gl, ldst + wo + 8192);
                gl16(gv, ldst + wo + 16384);
            }

            if (kb <= qdiv) {
                const int bA = b0 + ro, bB = b1 + ro;
                f32x4 sc[4] = {};
                __builtin_amdgcn_s_setprio(1);
                #pragma unroll
                for (int kk = 0; kk < 2; kk++) {
                    const int bb = kk ? bB : bA;
                    bf16x8 bh8[4], bl8[4];
                    #pragma unroll
                    for (int nt = 0; nt < 4; nt++) {
                        bh8[nt] = *reinterpret_cast<const bf16x8*>(LDS + bb + nt * 2048);
                        bl8[nt] = *reinterpret_cast<const bf16x8*>(LDS + bb + nt * 2048 + 8192);
                    }
                    #pragma unroll
                    for (int nt = 0; nt < 4; nt++) {
                        sc[nt] = __builtin_amdgcn_mfma_f32_16x16x32_bf16(bh8[nt], qh[kk], sc[nt], 0, 0, 0);
                        sc[nt] = __builtin_amdgcn_mfma_f32_16x16x32_bf16(bl8[nt], qh[kk], sc[nt], 0, 0, 0);
                        sc[nt] = __builtin_amdgcn_mfma_f32_16x16x32_bf16(bh8[nt], ql[kk], sc[nt], 0, 0, 0);
                    }
                }
                __builtin_amdgcn_s_setprio(0);

                if (kb == qdiv) {
                    #pragma unroll
                    for (int nt = 0; nt < 4; nt++)
                        #pragma unroll
                        for (int j = 0; j < 4; j++) {
                            int kg = kb * 64 + nt * 16 + 4 * lg + j;
                            if (kg > qg) sc[nt][j] = NEG_INF;
                        }
                }

                float mA = fmaxf(fmaxf(sc[0][0], sc[0][1]), sc[0][2]);
                float mB = fmaxf(fmaxf(sc[0][3], sc[1][0]), sc[1][1]);
                float mC = fmaxf(fmaxf(sc[1][2], sc[1][3]), sc[2][0]);
                float mD = fmaxf(fmaxf(sc[2][1], sc[2][2]), sc[2][3]);
                float mE = fmaxf(fmaxf(sc[3][0], sc[3][1]), sc[3][2]);
                float lm = fmaxf(fmaxf(fmaxf(mA, mB), fmaxf(mC, mD)),
                                 fmaxf(mE, sc[3][3]));
                if (__any(lm > mrow + DEFER_THR)) {
                    float pm = lm;
                    pm = fmaxf(pm, __shfl_xor(pm, 16));
                    pm = fmaxf(pm, __shfl_xor(pm, 32));
                    float mnew = fmaxf(mrow, pm);
                    float alpha = __builtin_amdgcn_exp2f((mrow - mnew) * L2E);
                    mrow = mnew;
                    negmL2 = -mnew * L2E;
                    lsum2 *= alpha;
                    #pragma unroll
                    for (int nt = 0; nt < 4; nt++)
                        #pragma unroll
                        for (int j = 0; j < 4; j++)
                            accO[nt][j] *= alpha;
                }

                f32x2 pr2[8];
                #pragma unroll
                for (int nt = 0; nt < 4; nt++) {
                    pr2[2 * nt]     = __builtin_shufflevector(sc[nt], sc[nt], 0, 1);
                    pr2[2 * nt + 1] = __builtin_shufflevector(sc[nt], sc[nt], 2, 3);
                }
                const f32x2 vL2E = {L2E, L2E};
                const f32x2 vneg = {negmL2, negmL2};
                f32x2 ts2 = {0.0f, 0.0f};
                #pragma unroll
                for (int i = 0; i < 8; i++) {
                    f32x2 a = __builtin_elementwise_fma(pr2[i], vL2E, vneg);
                    f32x2 e;
                    e.x = __builtin_amdgcn_exp2f(a.x);
                    e.y = __builtin_amdgcn_exp2f(a.y);
                    pr2[i] = e;
                    ts2 += e;
                }
                lsum2 += ts2;

                unsigned int w[4][2];
                #pragma unroll
                for (int nt = 0; nt < 4; nt++)
                    #pragma unroll
                    for (int p = 0; p < 2; p++) {
                        unsigned int d;
                        asm("v_cvt_pk_bf16_f32 %0, %1, %2"
                            : "=v"(d) : "v"(pr2[2 * nt + p].x), "v"(pr2[2 * nt + p].y));
                        w[nt][p] = d;
                    }
                bf16x8 bp[2];
                #pragma unroll
                for (int kk = 0; kk < 2; kk++) {
                    unsigned int a0 = w[2 * kk][0], bq0 = w[2 * kk + 1][0];
                    unsigned int a1 = w[2 * kk][1], bq1 = w[2 * kk + 1][1];
                    asm("v_permlane32_swap_b32 %0, %1" : "+v"(a0), "+v"(bq0));
                    asm("v_permlane16_swap_b32 %0, %1" : "+v"(a0), "+v"(bq0));
                    asm("v_permlane32_swap_b32 %0, %1" : "+v"(a1), "+v"(bq1));
                    asm("v_permlane16_swap_b32 %0, %1" : "+v"(a1), "+v"(bq1));
                    union { unsigned int u[4]; bf16x8 v; } cvt;
                    cvt.u[0] = a0; cvt.u[1] = a1; cvt.u[2] = bq0; cvt.u[3] = bq1;
                    bp[kk] = cvt.v;
                }

                __builtin_amdgcn_s_setprio(1);
                #pragma unroll
                for (int kk = 0; kk < 2; kk++) {
                    const int bb = kk ? bB : bA;
                    #pragma unroll
                    for (int nt = 0; nt < 4; nt++) {
                        bf16x8 bv = *reinterpret_cast<const bf16x8*>(LDS + bb + nt * 2048 + 16384);
                        accO[nt] = __builtin_amdgcn_mfma_f32_16x16x32_bf16(bv, bp[kk], accO[nt], 0, 0, 0);
                    }
                }
                __builtin_amdgcn_s_setprio(0);
            }

            __syncthreads();
        }

        float ps = lsum2.x + lsum2.y;
        ps += __shfl_xor(ps, 16);
        ps += __shfl_xor(ps, 32);
        float inv = 1.0f / ps;
        size_t rowbase = (size_t)((bh >> 4) * 2048 + qg) * 1024 + (bh & 15) * 64;
        #pragma unroll
        for (int nt = 0; nt < 4; nt++) {
            bf16x4 o;
            #pragma unroll
            for (int j = 0; j < 4; j++) o[j] = (bf16)(accO[nt][j] * inv);
            *reinterpret_cast<bf16x4*>(hd + rowbase + nt * 16 + 4 * lg) = o;
        }
    }
}

// ---------------- launcher ----------------

extern "C" void kernel_launch(void* const* d_in, const int* in_sizes, int n_in,
                              void* d_out, int out_size, void* d_ws, size_t ws_size,
                              hipStream_t stream) {
    const float* x  = (const float*)d_in[0];
    const float* Wq = (const float*)d_in[1];
    const float* Wk = (const float*)d_in[2];
    const float* Wv = (const float*)d_in[3];
    const float* W0 = (const float*)d_in[4];
    float* out = (float*)d_out;

    char* ws = (char*)d_ws;
    bf16* w0t = (bf16*)(ws + 0);
    bf16* Qhi = (bf16*)(ws + 2097152);
    bf16* Qlo = (bf16*)(ws + 18874368);
    bf16* Khi = (bf16*)(ws + 35651584);
    bf16* Klo = (bf16*)(ws + 52428800);
    bf16* Vtb = (bf16*)(ws + 69206016);
    bf16* whi = (bf16*)(ws + 85983232);
    bf16* wlo = (bf16*)(ws + 92274688);
    bf16* hd  = (bf16*)(ws + 85983232);     // aliases whi/wlo (dead after GEMMs)
    if (ws_size < 102760448u) return;       // need 98 MiB scratch

    // xh/xl live in d_out (32 MiB exact); dead before gemm2<1> overwrites d_out.
    bf16* xh = (bf16*)d_out;
    bf16* xl = xh + 8388608;

    k_prep    <<<9216, 256, 0, stream>>>(x, Wq, Wk, Wv, W0, xh, xl, whi, wlo, w0t);
    k_gemm3   <<<dim3(64, 16), 256, 0, stream>>>(xh, xl, whi, wlo, Qhi, Qlo, Khi, Klo);
    k_gemm2<0><<<dim3(64, 16), 256, 0, stream>>>(xh, whi + 2048 * 1024, Vtb, nullptr);
    k_attn    <<<512, 512, 0, stream>>>(Qhi, Qlo, Khi, Klo, Vtb, hd);
    k_gemm2<1><<<dim3(64, 16), 256, 0, stream>>>(hd, w0t, nullptr, out);
}

// Round 17
// 239.988 us; speedup vs baseline: 1.0949x; 1.0949x over previous
//
#include <hip/hip_runtime.h>

typedef __bf16 bf16;
typedef __bf16 bf16x4 __attribute__((ext_vector_type(4)));
typedef __bf16 bf16x8 __attribute__((ext_vector_type(8)));
typedef float  f32x2  __attribute__((ext_vector_type(2)));
typedef float  f32x4  __attribute__((ext_vector_type(4)));

#define NEG_INF (-__builtin_inff())
#define L2E 1.44269504088896f
#define DEFER_THR 5.545177444479562f   /* 8 / log2(e): exp2 exponent bound 8 */

__device__ __forceinline__ void gl16(const void* g, void* l) {
    __builtin_amdgcn_global_load_lds(
        (const __attribute__((address_space(1))) void*)g,
        (__attribute__((address_space(3))) void*)l, 16, 0, 0);
}

// ---------------- fused prep: x split + W_qkv transpose-split + W_0 transpose ----------------
// grid 9216 x 256: [0,8192) split_x; [8192,8960) cvt_wqkv; [8960,9216) cvt_w0
__global__ void k_prep(const float* __restrict__ x,
                       const float* __restrict__ wq, const float* __restrict__ wk,
                       const float* __restrict__ wv, const float* __restrict__ w0,
                       bf16* __restrict__ xh, bf16* __restrict__ xl,
                       bf16* __restrict__ ohi, bf16* __restrict__ olo,
                       bf16* __restrict__ w0t) {
    __shared__ float tile[64][65];
    const int bid = blockIdx.x;
    const int t = threadIdx.x;
    if (bid < 8192) {
        int i = (bid * 256 + t) * 4;
        float4 v = *reinterpret_cast<const float4*>(x + i);
        float a[4] = {v.x, v.y, v.z, v.w};
        bf16x4 h, l;
        #pragma unroll
        for (int e = 0; e < 4; e++) {
            bf16 hh = (bf16)a[e];
            h[e] = hh;
            l[e] = (bf16)(a[e] - (float)hh);
        }
        *reinterpret_cast<bf16x4*>(xh + i) = h;
        *reinterpret_cast<bf16x4*>(xl + i) = l;
    } else if (bid < 8960) {
        const int idx = bid - 8192;
        const int d0 = (idx & 15) * 64, h = (idx >> 4) & 15, proj = idx >> 8;
        const float* w = (proj == 0) ? wq : ((proj == 1) ? wk : wv);
        {
            int k = t & 63, dr = t >> 6;
            #pragma unroll
            for (int i = 0; i < 16; i++) {
                int dl = i * 4 + dr;
                tile[dl][k] = w[(size_t)(h * 1024 + d0 + dl) * 64 + k];
            }
        }
        __syncthreads();
        {
            int dl = t & 63, kr = t >> 6;
            #pragma unroll
            for (int i = 0; i < 16; i++) {
                int k = i * 4 + kr;
                float v = tile[dl][k];
                bf16 hi = (bf16)v;
                size_t o = (size_t)(proj * 1024 + h * 64 + k) * 1024 + d0 + dl;
                ohi[o] = hi;
                olo[o] = (bf16)(v - (float)hi);
            }
        }
    } else {
        const int idx = bid - 8960;
        const int n0 = (idx & 15) * 64, c0 = (idx >> 4) * 64;
        {
            int n = t & 63, cr = t >> 6;
            #pragma unroll
            for (int i = 0; i < 16; i++) {
                int cl = i * 4 + cr;
                tile[cl][n] = w0[(size_t)(c0 + cl) * 1024 + n0 + n];
            }
        }
        __syncthreads();
        {
            int cl = t & 63, nr = t >> 6;
            #pragma unroll
            for (int i = 0; i < 16; i++) {
                int nl = i * 4 + nr;
                w0t[(size_t)(n0 + nl) * 1024 + c0 + cl] = (bf16)tile[cl][nl];
            }
        }
    }
}

// ---------------- projection GEMM, Q/K (split-bf16, 3-pass, global_load_lds) ----------------
// A planes: xh/xl [8192][1024]; B planes: whi/wlo rows [0,2048). grid (64,16).
__global__ __launch_bounds__(256)
void k_gemm3(const bf16* __restrict__ Ah, const bf16* __restrict__ Al,
             const bf16* __restrict__ Bh, const bf16* __restrict__ Bl,
             bf16* __restrict__ Qhi, bf16* __restrict__ Qlo,
             bf16* __restrict__ Khi, bf16* __restrict__ Klo)
{
    __shared__ char LDS[65536];   // A-hi | A-lo | B-hi | B-lo, 16K each
    const int t = threadIdx.x;
    const int m0 = blockIdx.x * 128;
    const int n0 = blockIdx.y * 128;
    const int wid = t >> 6, lane = t & 63, lr = lane & 15, lg = lane >> 4;
    const int wm = wid >> 1, wn = wid & 1;

    // pre-swizzled per-lane source offset: row' = lane>>3, col8 = (lane&7)^(lane>>3)
    const int eoff = (lane >> 3) * 1024 + (((lane & 7) ^ (lane >> 3)) * 8);
    const bf16* pAh = Ah + (size_t)m0 * 1024 + eoff;
    const bf16* pAl = Al + (size_t)m0 * 1024 + eoff;
    const bf16* pBh = Bh + (size_t)n0 * 1024 + eoff;
    const bf16* pBl = Bl + (size_t)n0 * 1024 + eoff;

    f32x4 acc[4][4] = {};

    for (int k0 = 0; k0 < 1024; k0 += 64) {
        #pragma unroll
        for (int i = 0; i < 4; i++) {
            const int r0 = (wid * 4 + i) * 8;          // wave-uniform row group
            const size_t gofs = (size_t)r0 * 1024 + k0;
            char* ld = LDS + r0 * 128;
            gl16(pAh + gofs, ld);
            gl16(pAl + gofs, ld + 16384);
            gl16(pBh + gofs, ld + 32768);
            gl16(pBl + gofs, ld + 49152);
        }
        __syncthreads();
        #pragma unroll
        for (int kk = 0; kk < 2; kk++) {
            bf16x8 ah[4], al[4], bh[4], bl[4];
            #pragma unroll
            for (int mt = 0; mt < 4; mt++) {
                int row = wm * 64 + mt * 16 + lr;
                int off = row * 128 + (((kk * 4 + lg) * 16) ^ ((row & 7) << 4));
                ah[mt] = *reinterpret_cast<const bf16x8*>(LDS + off);
                al[mt] = *reinterpret_cast<const bf16x8*>(LDS + 16384 + off);
            }
            #pragma unroll
            for (int nt = 0; nt < 4; nt++) {
                int row = wn * 64 + nt * 16 + lr;
                int off = row * 128 + (((kk * 4 + lg) * 16) ^ ((row & 7) << 4));
                bh[nt] = *reinterpret_cast<const bf16x8*>(LDS + 32768 + off);
                bl[nt] = *reinterpret_cast<const bf16x8*>(LDS + 49152 + off);
            }
            #pragma unroll
            for (int mt = 0; mt < 4; mt++)
                #pragma unroll
                for (int nt = 0; nt < 4; nt++) {
                    acc[mt][nt] = __builtin_amdgcn_mfma_f32_16x16x32_bf16(
                        ah[mt], bh[nt], acc[mt][nt], 0, 0, 0);
                    acc[mt][nt] = __builtin_amdgcn_mfma_f32_16x16x32_bf16(
                        ah[mt], bl[nt], acc[mt][nt], 0, 0, 0);
                    acc[mt][nt] = __builtin_amdgcn_mfma_f32_16x16x32_bf16(
                        al[mt], bh[nt], acc[mt][nt], 0, 0, 0);
                }
        }
        __syncthreads();
    }

    #pragma unroll
    for (int mt = 0; mt < 4; mt++)
        #pragma unroll
        for (int nt = 0; nt < 4; nt++)
            #pragma unroll
            for (int j = 0; j < 4; j++) {
                int m = m0 + wm * 64 + mt * 16 + lg * 4 + j;
                int n = n0 + wn * 64 + nt * 16 + lr;
                float v = acc[mt][nt][j];
                int b = m >> 11, s = m & 2047;
                if (n < 1024) {
                    int h = n >> 6, k = n & 63;
                    size_t idx = ((size_t)(b * 16 + h) * 2048 + s) * 64 + k;
                    float vs = v * 0.125f;
                    bf16 hi = (bf16)vs;
                    Qhi[idx] = hi;
                    Qlo[idx] = (bf16)(vs - (float)hi);
                } else {
                    int n2 = n - 1024, h = n2 >> 6, k = n2 & 63;
                    size_t idx = ((size_t)(b * 16 + h) * 2048 + s) * 64 + k;
                    bf16 hi = (bf16)v;
                    Khi[idx] = hi;
                    Klo[idx] = (bf16)(v - (float)hi);
                }
            }
}

// ---------------- 2-plane bf16 GEMM (global_load_lds) ----------------
// MODE 0: V^T scatter epilogue; MODE 1: fp32 Out epilogue.
template<int MODE>
__global__ __launch_bounds__(256)
void k_gemm2(const bf16* __restrict__ A, const bf16* __restrict__ Bt,
             bf16* __restrict__ Vtb, float* __restrict__ Out)
{
    __shared__ char LDS[32768];   // A | B, 16K each
    const int t = threadIdx.x;
    const int m0 = blockIdx.x * 128;
    const int n0 = blockIdx.y * 128;
    const int wid = t >> 6, lane = t & 63, lr = lane & 15, lg = lane >> 4;
    const int wm = wid >> 1, wn = wid & 1;

    const int eoff = (lane >> 3) * 1024 + (((lane & 7) ^ (lane >> 3)) * 8);
    const bf16* pA = A + (size_t)m0 * 1024 + eoff;
    const bf16* pB = Bt + (size_t)n0 * 1024 + eoff;

    f32x4 acc[4][4] = {};

    for (int k0 = 0; k0 < 1024; k0 += 64) {
        #pragma unroll
        for (int i = 0; i < 4; i++) {
            const int r0 = (wid * 4 + i) * 8;
            const size_t gofs = (size_t)r0 * 1024 + k0;
            char* ld = LDS + r0 * 128;
            gl16(pA + gofs, ld);
            gl16(pB + gofs, ld + 16384);
        }
        __syncthreads();
        #pragma unroll
        for (int kk = 0; kk < 2; kk++) {
            bf16x8 af[4], bfr[4];
            #pragma unroll
            for (int mt = 0; mt < 4; mt++) {
                int row = wm * 64 + mt * 16 + lr;
                af[mt] = *reinterpret_cast<const bf16x8*>(
                    LDS + row * 128 + (((kk * 4 + lg) * 16) ^ ((row & 7) << 4)));
            }
            #pragma unroll
            for (int nt = 0; nt < 4; nt++) {
                int row = wn * 64 + nt * 16 + lr;
                bfr[nt] = *reinterpret_cast<const bf16x8*>(
                    LDS + 16384 + row * 128 + (((kk * 4 + lg) * 16) ^ ((row & 7) << 4)));
            }
            #pragma unroll
            for (int mt = 0; mt < 4; mt++)
                #pragma unroll
                for (int nt = 0; nt < 4; nt++)
                    acc[mt][nt] = __builtin_amdgcn_mfma_f32_16x16x32_bf16(
                        af[mt], bfr[nt], acc[mt][nt], 0, 0, 0);
        }
        __syncthreads();
    }

    #pragma unroll
    for (int mt = 0; mt < 4; mt++)
        #pragma unroll
        for (int nt = 0; nt < 4; nt++)
            #pragma unroll
            for (int j = 0; j < 4; j++) {
                int m = m0 + wm * 64 + mt * 16 + lg * 4 + j;
                int nl = n0 + wn * 64 + nt * 16 + lr;
                if (MODE == 0) {
                    int b = m >> 11, s = m & 2047;
                    int h = nl >> 6, dv = nl & 63;
                    Vtb[((size_t)(b * 16 + h) * 64 + dv) * 2048 + s] = (bf16)acc[mt][nt][j];
                } else {
                    Out[(size_t)m * 1024 + nl] = acc[mt][nt][j];
                }
            }
}

// ---------------- flash attention v10: gl_lds staging ----------------
__global__ __launch_bounds__(512, 4)
void k_attn(const bf16* __restrict__ Qhi, const bf16* __restrict__ Qlo,
            const bf16* __restrict__ Khi, const bf16* __restrict__ Klo,
            const bf16* __restrict__ Vtb, bf16* __restrict__ hd)
{
    __shared__ char LDS[49152];   // buf (24K): K-hi | K-lo | V ; x2 buffers
    const int bid = blockIdx.x;
    const int x7 = bid & 7, k6 = bid >> 3;
    const int hh = k6 >> 3, pr = k6 & 7;
    const int bh = x7 * 8 + hh;
    const int t = threadIdx.x, wid = t >> 6, lane = t & 63, lr = lane & 15, lg = lane >> 4;
    const bf16* Qhp = Qhi + (size_t)bh * 131072;
    const bf16* Qlp = Qlo + (size_t)bh * 131072;
    const bf16* Kbase = Khi + (size_t)bh * 131072;
    const bf16* Lbase = Klo + (size_t)bh * 131072;
    const bf16* Vbase = Vtb + (size_t)bh * 131072;

    const int swc = (lr & 7) << 4;
    const int b0 = lr * 128 + ((lg * 16) ^ swc);
    const int b1 = lr * 128 + ((64 + lg * 16) ^ swc);

    const int r = t >> 3, c8 = t & 7;
    const int ssw = ((c8 ^ (r & 7)) * 8);
    const int kso = r * 64 + ssw;
    const int vso = r * 2048 + ssw;
    char* const ldst = (char*)LDS + (t >> 6) * 1024 + 0;

    #pragma unroll 1
    for (int pass = 0; pass < 2; pass++) {
        const int qB = pass ? pr : 15 - pr;
        const int q0 = qB * 128 + wid * 16;
        const int qdiv = q0 >> 6;
        const int kbmax = 2 * qB + 1;
        const int qg = q0 + lr;

        bf16x8 qh[2], ql[2];
        #pragma unroll
        for (int kk = 0; kk < 2; kk++) {
            size_t off = (size_t)(q0 + lr) * 64 + kk * 32 + lg * 8;
            qh[kk] = *reinterpret_cast<const bf16x8*>(Qhp + off);
            ql[kk] = *reinterpret_cast<const bf16x8*>(Qlp + off);
        }

        const bf16* gk = Kbase + kso;
        const bf16* gl = Lbase + kso;
        const bf16* gv = Vbase + vso;

        gl16(gk, ldst);
        gl16(gl, ldst + 8192);
        gl16(gv, ldst + 16384);
        __syncthreads();

        f32x4 accO[4] = {};
        float mrow = NEG_INF;
        float negmL2 = NEG_INF;
        f32x2 lsum2 = {0.0f, 0.0f};

        for (int kb = 0; kb <= kbmax; kb++) {
            const int ro = (kb & 1) ? 24576 : 0;
            const int wo = 24576 - ro;
            if (kb < kbmax) {
                gk += 4096; gl += 4096; gv += 64;
                gl16(gk, ldst + wo);
                gl16(gl, ldst + wo + 8192);
                gl16(gv, ldst + wo + 16384);
            }

            if (kb <= qdiv) {
                const int bA = b0 + ro, bB = b1 + ro;
                f32x4 sc[4] = {};
                __builtin_amdgcn_s_setprio(1);
                #pragma unroll
                for (int kk = 0; kk < 2; kk++) {
                    const int bb = kk ? bB : bA;
                    bf16x8 bh8[4], bl8[4];
                    #pragma unroll
                    for (int nt = 0; nt < 4; nt++) {
                        bh8[nt] = *reinterpret_cast<const bf16x8*>(LDS + bb + nt * 2048);
                        bl8[nt] = *reinterpret_cast<const bf16x8*>(LDS + bb + nt * 2048 + 8192);
                    }
                    #pragma unroll
                    for (int nt = 0; nt < 4; nt++) {
                        sc[nt] = __builtin_amdgcn_mfma_f32_16x16x32_bf16(bh8[nt], qh[kk], sc[nt], 0, 0, 0);
                        sc[nt] = __builtin_amdgcn_mfma_f32_16x16x32_bf16(bl8[nt], qh[kk], sc[nt], 0, 0, 0);
                        sc[nt] = __builtin_amdgcn_mfma_f32_16x16x32_bf16(bh8[nt], ql[kk], sc[nt], 0, 0, 0);
                    }
                }
                __builtin_amdgcn_s_setprio(0);

                if (kb == qdiv) {
                    #pragma unroll
                    for (int nt = 0; nt < 4; nt++)
                        #pragma unroll
                        for (int j = 0; j < 4; j++) {
                            int kg = kb * 64 + nt * 16 + 4 * lg + j;
                            if (kg > qg) sc[nt][j] = NEG_INF;
                        }
                }

                float mA = fmaxf(fmaxf(sc[0][0], sc[0][1]), sc[0][2]);
                float mB = fmaxf(fmaxf(sc[0][3], sc[1][0]), sc[1][1]);
                float mC = fmaxf(fmaxf(sc[1][2], sc[1][3]), sc[2][0]);
                float mD = fmaxf(fmaxf(sc[2][1], sc[2][2]), sc[2][3]);
                float mE = fmaxf(fmaxf(sc[3][0], sc[3][1]), sc[3][2]);
                float lm = fmaxf(fmaxf(fmaxf(mA, mB), fmaxf(mC, mD)),
                                 fmaxf(mE, sc[3][3]));
                if (__any(lm > mrow + DEFER_THR)) {
                    float pm = lm;
                    pm = fmaxf(pm, __shfl_xor(pm, 16));
                    pm = fmaxf(pm, __shfl_xor(pm, 32));
                    float mnew = fmaxf(mrow, pm);
                    float alpha = __builtin_amdgcn_exp2f((mrow - mnew) * L2E);
                    mrow = mnew;
                    negmL2 = -mnew * L2E;
                    lsum2 *= alpha;
                    #pragma unroll
                    for (int nt = 0; nt < 4; nt++)
                        #pragma unroll
                        for (int j = 0; j < 4; j++)
                            accO[nt][j] *= alpha;
                }

                f32x2 pr2[8];
                #pragma unroll
                for (int nt = 0; nt < 4; nt++) {
                    pr2[2 * nt]     = __builtin_shufflevector(sc[nt], sc[nt], 0, 1);
                    pr2[2 * nt + 1] = __builtin_shufflevector(sc[nt], sc[nt], 2, 3);
                }
                const f32x2 vL2E = {L2E, L2E};
                const f32x2 vneg = {negmL2, negmL2};
                f32x2 ts2 = {0.0f, 0.0f};
                #pragma unroll
                for (int i = 0; i < 8; i++) {
                    f32x2 a = __builtin_elementwise_fma(pr2[i], vL2E, vneg);
                    f32x2 e;
                    e.x = __builtin_amdgcn_exp2f(a.x);
                    e.y = __builtin_amdgcn_exp2f(a.y);
                    pr2[i] = e;
                    ts2 += e;
                }
                lsum2 += ts2;

                unsigned int w[4][2];
                #pragma unroll
                for (int nt = 0; nt < 4; nt++)
                    #pragma unroll
                    for (int p = 0; p < 2; p++) {
                        unsigned int d;
                        asm("v_cvt_pk_bf16_f32 %0, %1, %2"
                            : "=v"(d) : "v"(pr2[2 * nt + p].x), "v"(pr2[2 * nt + p].y));
                        w[nt][p] = d;
                    }
                bf16x8 bp[2];
                #pragma unroll
                for (int kk = 0; kk < 2; kk++) {
                    unsigned int a0 = w[2 * kk][0], bq0 = w[2 * kk + 1][0];
                    unsigned int a1 = w[2 * kk][1], bq1 = w[2 * kk + 1][1];
                    asm("v_permlane32_swap_b32 %0, %1" : "+v"(a0), "+v"(bq0));
                    asm("v_permlane16_swap_b32 %0, %1" : "+v"(a0), "+v"(bq0));
                    asm("v_permlane32_swap_b32 %0, %1" : "+v"(a1), "+v"(bq1));
                    asm("v_permlane16_swap_b32 %0, %1" : "+v"(a1), "+v"(bq1));
                    union { unsigned int u[4]; bf16x8 v; } cvt;
                    cvt.u[0] = a0; cvt.u[1] = a1; cvt.u[2] = bq0; cvt.u[3] = bq1;
                    bp[kk] = cvt.v;
                }

                __builtin_amdgcn_s_setprio(1);
                #pragma unroll
                for (int kk = 0; kk < 2; kk++) {
                    const int bb = kk ? bB : bA;
                    #pragma unroll
                    for (int nt = 0; nt < 4; nt++) {
                        bf16x8 bv = *reinterpret_cast<const bf16x8*>(LDS + bb + nt * 2048 + 16384);
                        accO[nt] = __builtin_amdgcn_mfma_f32_16x16x32_bf16(bv, bp[kk], accO[nt], 0, 0, 0);
                    }
                }
                __builtin_amdgcn_s_setprio(0);
            }

            __syncthreads();
        }

        float ps = lsum2.x + lsum2.y;
        ps += __shfl_xor(ps, 16);
        ps += __shfl_xor(ps, 32);
        float inv = 1.0f / ps;
        size_t rowbase = (size_t)((bh >> 4) * 2048 + qg) * 1024 + (bh & 15) * 64;
        #pragma unroll
        for (int nt = 0; nt < 4; nt++) {
            bf16x4 o;
            #pragma unroll
            for (int j = 0; j < 4; j++) o[j] = (bf16)(accO[nt][j] * inv);
            *reinterpret_cast<bf16x4*>(hd + rowbase + nt * 16 + 4 * lg) = o;
        }
    }
}

// ---------------- launcher ----------------

extern "C" void kernel_launch(void* const* d_in, const int* in_sizes, int n_in,
                              void* d_out, int out_size, void* d_ws, size_t ws_size,
                              hipStream_t stream) {
    const float* x  = (const float*)d_in[0];
    const float* Wq = (const float*)d_in[1];
    const float* Wk = (const float*)d_in[2];
    const float* Wv = (const float*)d_in[3];
    const float* W0 = (const float*)d_in[4];
    float* out = (float*)d_out;

    char* ws = (char*)d_ws;
    bf16* w0t = (bf16*)(ws + 0);
    bf16* Qhi = (bf16*)(ws + 2097152);
    bf16* Qlo = (bf16*)(ws + 18874368);
    bf16* Khi = (bf16*)(ws + 35651584);
    bf16* Klo = (bf16*)(ws + 52428800);
    bf16* Vtb = (bf16*)(ws + 69206016);
    bf16* whi = (bf16*)(ws + 85983232);
    bf16* wlo = (bf16*)(ws + 92274688);
    bf16* hd  = (bf16*)(ws + 85983232);     // aliases whi/wlo (dead after GEMMs)
    if (ws_size < 102760448u) return;       // need 98 MiB scratch

    // xh/xl live in d_out (32 MiB exact); dead before gemm2<1> overwrites d_out.
    bf16* xh = (bf16*)d_out;
    bf16* xl = xh + 8388608;

    k_prep    <<<9216, 256, 0, stream>>>(x, Wq, Wk, Wv, W0, xh, xl, whi, wlo, w0t);
    k_gemm3   <<<dim3(64, 16), 256, 0, stream>>>(xh, xl, whi, wlo, Qhi, Qlo, Khi, Klo);
    k_gemm2<0><<<dim3(64, 8), 256, 0, stream>>>(xh, whi + 2048 * 1024, Vtb, nullptr);
    k_attn    <<<512, 512, 0, stream>>>(Qhi, Qlo, Khi, Klo, Vtb, hd);
    k_gemm2<1><<<dim3(64, 8), 256, 0, stream>>>(hd, w0t, nullptr, out);
}